// Round 1
// baseline (3036.944 us; speedup 1.0000x reference)
//
#include <hip/hip_runtime.h>
#include <math.h>

#define S_LEN 2048
#define EMB   1024
#define NHEAD 8
#define DH    128
#define E3    3072

// ---------------------------------------------------------------------------
// Kernel 1: gate projections. One wave per (t, h): ig = gate_in@Wi.T + bi,
// lf = log_sigmoid(gate_in@Wf.T + bf). gate_in = concat(q,k,v) row t.
// ---------------------------------------------------------------------------
__global__ __launch_bounds__(64) void gates_kernel(
    const float* __restrict__ q, const float* __restrict__ k,
    const float* __restrict__ v,
    const float* __restrict__ Wi, const float* __restrict__ bi,
    const float* __restrict__ Wf, const float* __restrict__ bf,
    float* __restrict__ ig, float* __restrict__ lf)
{
    const int t = blockIdx.x, h = blockIdx.y, lane = threadIdx.x;
    const float* wi = Wi + h * E3;
    const float* wf = Wf + h * E3;
    const float* qr = q + (size_t)t * EMB;
    const float* kr = k + (size_t)t * EMB;
    const float* vr = v + (size_t)t * EMB;
    float si = 0.f, sf = 0.f;
    for (int e = lane; e < EMB; e += 64) { float g = qr[e]; si += g * wi[e];          sf += g * wf[e]; }
    for (int e = lane; e < EMB; e += 64) { float g = kr[e]; si += g * wi[EMB + e];    sf += g * wf[EMB + e]; }
    for (int e = lane; e < EMB; e += 64) { float g = vr[e]; si += g * wi[2*EMB + e];  sf += g * wf[2*EMB + e]; }
    for (int o = 32; o > 0; o >>= 1) {
        si += __shfl_down(si, o, 64);
        sf += __shfl_down(sf, o, 64);
    }
    if (lane == 0) {
        ig[h * S_LEN + t] = si + bi[h];
        float x = sf + bf[h];
        // stable log_sigmoid
        lf[h * S_LEN + t] = fminf(x, 0.f) - log1pf(expf(-fabsf(x)));
    }
}

// ---------------------------------------------------------------------------
// Kernel 2: per-head inclusive cumsum of lf -> F[h][0..S], F[h][0]=0.
// One block of 256 per head, 8 elems/thread + Hillis-Steele scan of sums.
// ---------------------------------------------------------------------------
__global__ __launch_bounds__(256) void cumsum_kernel(
    const float* __restrict__ lf, float* __restrict__ F)
{
    const int h = blockIdx.x, tid = threadIdx.x;
    __shared__ float ssum[256];
    float loc[8];
    const int base = tid * 8;
    float s = 0.f;
    for (int i = 0; i < 8; i++) { s += lf[h * S_LEN + base + i]; loc[i] = s; }
    ssum[tid] = s;
    __syncthreads();
    for (int o = 1; o < 256; o <<= 1) {
        float add = (tid >= o) ? ssum[tid - o] : 0.f;
        __syncthreads();
        ssum[tid] += add;
        __syncthreads();
    }
    float prev = (tid > 0) ? ssum[tid - 1] : 0.f;
    float* Fh = F + h * (S_LEN + 1);
    if (tid == 0) Fh[0] = 0.f;
    for (int i = 0; i < 8; i++) Fh[base + i + 1] = prev + loc[i];
}

// ---------------------------------------------------------------------------
// Kernel 3: main mLSTM parallel attention. Block = 128 threads = one (h,s)
// row; thread d owns output dim d. K staged in LDS (pad 129 -> 2-way bank
// aliasing only, free). Online max/sum over t-tiles of 64.
// ---------------------------------------------------------------------------
__global__ __launch_bounds__(128) void mlstm_main(
    const float* __restrict__ q, const float* __restrict__ k,
    const float* __restrict__ v,
    const float* __restrict__ ig, const float* __restrict__ F,
    float* __restrict__ out)
{
    const int s = blockIdx.x, h = blockIdx.y, tid = threadIdx.x;
    __shared__ float qrow[DH];
    __shared__ float Kt[64 * 129];
    __shared__ float cbuf[64];
    __shared__ float pdot[128];
    __shared__ float bcast[2];
    const float inv_sqrt_dh = 0.088388347648318447f; // 1/sqrt(128)
    const float* Fh  = F  + h * (S_LEN + 1);
    const float* igh = ig + h * S_LEN;
    qrow[tid] = q[(size_t)s * EMB + h * DH + tid];
    const float Fs1 = Fh[s + 1];
    float m = -INFINITY, l = 0.f, acc = 0.f;
    const int j    = tid & 63;
    const int half = tid >> 6;

    for (int tb = 0; tb <= s; tb += 64) {
        const int jmax = min(64, s - tb + 1);
        __syncthreads();                      // (A) prev-iter consumers done
        // --- stage K tile (64 rows x 128 cols), rows >= jmax zeroed ---
        for (int idx = tid; idx < 64 * DH; idx += 128) {
            int r = idx >> 7, c = idx & 127;
            Kt[r * 129 + c] = (r < jmax) ? k[(size_t)(tb + r) * EMB + h * DH + c] : 0.f;
        }
        __syncthreads();                      // (B)
        // --- partial qk dot: thread (j, half) covers d in [half*64, +64) ---
        {
            const float* krow = &Kt[j * 129 + half * 64];
            const float* qr   = &qrow[half * 64];
            float p = 0.f;
            #pragma unroll
            for (int d = 0; d < 64; d++) p += qr[d] * krow[d];
            pdot[tid] = p;
        }
        __syncthreads();                      // (C)
        // --- gate value + tile max (wave 0 only) ---
        float gval = -INFINITY;
        if (tid < 64) {
            if (j < jmax) {
                int t = tb + j;
                gval = Fs1 - Fh[t + 1] + igh[t];
            }
            float x = gval;
            for (int o = 32; o > 0; o >>= 1) x = fmaxf(x, __shfl_down(x, o, 64));
            if (j == 0) bcast[0] = x;
        }
        __syncthreads();                      // (D)
        const float m_new = fmaxf(m, bcast[0]);
        if (tid < 64) {
            float qk = pdot[j] + pdot[j + 64];
            float c  = (j < jmax) ? expf(gval - m_new) * qk * inv_sqrt_dh : 0.f;
            cbuf[j] = c;
            float x = c;
            for (int o = 32; o > 0; o >>= 1) x += __shfl_down(x, o, 64);
            if (j == 0) bcast[1] = x;
        }
        __syncthreads();                      // (E)
        const float tsum  = bcast[1];
        const float alpha = expf(m - m_new);  // first tile: exp(-inf)=0, safe
        m = m_new;
        l = l * alpha + tsum;
        acc *= alpha;
        // --- accumulate C*V: thread tid = dim d, coalesced global V reads ---
        const float* vbase = v + (size_t)tb * EMB + h * DH + tid;
        for (int jj = 0; jj < jmax; jj++)
            acc += cbuf[jj] * vbase[(size_t)jj * EMB];
    }
    const float norm = fmaxf(fabsf(l), expf(-m)) + 1e-6f;
    out[(size_t)s * EMB + h * DH + tid] = acc / norm;
}

// ---------------------------------------------------------------------------
// Kernel 4: in-place residual LayerNorm over rows of out: (x-mu)*rstd*(1+w).
// ---------------------------------------------------------------------------
__global__ __launch_bounds__(256) void ln_kernel(
    float* __restrict__ out, const float* __restrict__ lnw)
{
    const int s = blockIdx.x, tid = threadIdx.x;
    __shared__ float red[4];
    float x[4];
    float sum = 0.f;
    #pragma unroll
    for (int i = 0; i < 4; i++) {
        x[i] = out[(size_t)s * EMB + tid + i * 256];
        sum += x[i];
    }
    for (int o = 32; o > 0; o >>= 1) sum += __shfl_down(sum, o, 64);
    if ((tid & 63) == 0) red[tid >> 6] = sum;
    __syncthreads();
    sum = red[0] + red[1] + red[2] + red[3];
    const float mu = sum * (1.f / EMB);
    float vs = 0.f;
    #pragma unroll
    for (int i = 0; i < 4; i++) { float d = x[i] - mu; vs += d * d; }
    __syncthreads();
    for (int o = 32; o > 0; o >>= 1) vs += __shfl_down(vs, o, 64);
    if ((tid & 63) == 0) red[tid >> 6] = vs;
    __syncthreads();
    vs = red[0] + red[1] + red[2] + red[3];
    const float rstd = rsqrtf(vs * (1.f / EMB) + 1e-5f);
    #pragma unroll
    for (int i = 0; i < 4; i++) {
        int c = tid + i * 256;
        out[(size_t)s * EMB + c] = (x[i] - mu) * rstd * (1.f + lnw[c]);
    }
}

// ---------------------------------------------------------------------------
extern "C" void kernel_launch(void* const* d_in, const int* in_sizes, int n_in,
                              void* d_out, int out_size, void* d_ws, size_t ws_size,
                              hipStream_t stream)
{
    const float* q   = (const float*)d_in[0];
    const float* k   = (const float*)d_in[1];
    const float* v   = (const float*)d_in[2];
    const float* Wi  = (const float*)d_in[3];
    const float* bi  = (const float*)d_in[4];
    const float* Wf  = (const float*)d_in[5];
    const float* bf  = (const float*)d_in[6];
    const float* lnw = (const float*)d_in[7];
    float* out = (float*)d_out;

    // workspace layout: ig[NH*S] | lf[NH*S] | F[NH*(S+1)]  (~197 KB)
    float* ws = (float*)d_ws;
    float* ig = ws;
    float* lf = ws + NHEAD * S_LEN;
    float* F  = ws + 2 * NHEAD * S_LEN;

    gates_kernel<<<dim3(S_LEN, NHEAD), 64, 0, stream>>>(q, k, v, Wi, bi, Wf, bf, ig, lf);
    cumsum_kernel<<<NHEAD, 256, 0, stream>>>(lf, F);
    mlstm_main<<<dim3(S_LEN, NHEAD), 128, 0, stream>>>(q, k, v, ig, F, out);
    ln_kernel<<<S_LEN, 256, 0, stream>>>(out, lnw);
}

// Round 3
// 353.958 us; speedup vs baseline: 8.5799x; 8.5799x over previous
//
#include <hip/hip_runtime.h>
#include <math.h>

#define S_LEN 2048
#define EMB   1024
#define NHEAD 8
#define DH    128
#define E3    3072
#define BM    32
#define QSTRIDE  136   // Q/K LDS row stride (elements): 272B rows -> 2-way banks, b128-aligned
#define VTSTRIDE 36    // V^T LDS row stride: 72B rows -> b64-aligned, conflict-light
#define PTSTRIDE 40    // P LDS row stride: 80B rows -> b128-aligned, 2-way banks

typedef __bf16 bf16x8 __attribute__((ext_vector_type(8)));
typedef __bf16 bf16x4 __attribute__((ext_vector_type(4)));
typedef float  f32x4  __attribute__((ext_vector_type(4)));

// ---------------------------------------------------------------------------
// Kernel 1: gate projections (unchanged). One wave per (t, h).
// ---------------------------------------------------------------------------
__global__ __launch_bounds__(64) void gates_kernel(
    const float* __restrict__ q, const float* __restrict__ k,
    const float* __restrict__ v,
    const float* __restrict__ Wi, const float* __restrict__ bi,
    const float* __restrict__ Wf, const float* __restrict__ bf,
    float* __restrict__ ig, float* __restrict__ lf)
{
    const int t = blockIdx.x, h = blockIdx.y, lane = threadIdx.x;
    const float* wi = Wi + h * E3;
    const float* wf = Wf + h * E3;
    const float* qr = q + (size_t)t * EMB;
    const float* kr = k + (size_t)t * EMB;
    const float* vr = v + (size_t)t * EMB;
    float si = 0.f, sf = 0.f;
    for (int e = lane; e < EMB; e += 64) { float g = qr[e]; si += g * wi[e];          sf += g * wf[e]; }
    for (int e = lane; e < EMB; e += 64) { float g = kr[e]; si += g * wi[EMB + e];    sf += g * wf[EMB + e]; }
    for (int e = lane; e < EMB; e += 64) { float g = vr[e]; si += g * wi[2*EMB + e];  sf += g * wf[2*EMB + e]; }
    for (int o = 32; o > 0; o >>= 1) {
        si += __shfl_down(si, o, 64);
        sf += __shfl_down(sf, o, 64);
    }
    if (lane == 0) {
        ig[h * S_LEN + t] = si + bi[h];
        float x = sf + bf[h];
        lf[h * S_LEN + t] = fminf(x, 0.f) - log1pf(expf(-fabsf(x)));
    }
}

// ---------------------------------------------------------------------------
// Kernel 2: per-head inclusive cumsum of lf -> F[h][0..S] (unchanged).
// ---------------------------------------------------------------------------
__global__ __launch_bounds__(256) void cumsum_kernel(
    const float* __restrict__ lf, float* __restrict__ F)
{
    const int h = blockIdx.x, tid = threadIdx.x;
    __shared__ float ssum[256];
    float loc[8];
    const int base = tid * 8;
    float s = 0.f;
    for (int i = 0; i < 8; i++) { s += lf[h * S_LEN + base + i]; loc[i] = s; }
    ssum[tid] = s;
    __syncthreads();
    for (int o = 1; o < 256; o <<= 1) {
        float add = (tid >= o) ? ssum[tid - o] : 0.f;
        __syncthreads();
        ssum[tid] += add;
        __syncthreads();
    }
    float prev = (tid > 0) ? ssum[tid - 1] : 0.f;
    float* Fh = F + h * (S_LEN + 1);
    if (tid == 0) Fh[0] = 0.f;
    for (int i = 0; i < 8; i++) Fh[base + i + 1] = prev + loc[i];
}

// ---------------------------------------------------------------------------
// Kernel 3: flash-style mLSTM attention, bf16 MFMA with SPLIT-BF16 Q/K.
// qk error was cancellation-amplified by the normalizer; Q,K are staged as
// hi/lo bf16 pairs and S = Qh*Kh + Qh*Kl + Ql*Kh (3 MFMAs) for ~fp32 qk.
// Grid (32, NHEAD), 256 threads (4 waves); wg x does Q-tiles {x, 63-x}.
// ---------------------------------------------------------------------------
__global__ __launch_bounds__(256) void mlstm_mfma(
    const float* __restrict__ q, const float* __restrict__ k,
    const float* __restrict__ v, const float* __restrict__ ig,
    const float* __restrict__ F, float* __restrict__ out)
{
    const int h    = blockIdx.y;
    const int tid  = threadIdx.x;
    const int lane = tid & 63, w = tid >> 6;
    const int quad = lane >> 4, l15 = lane & 15;
    const int mi = w & 1, ni = w >> 1;

    __shared__ __bf16 Qh[BM * QSTRIDE];
    __shared__ __bf16 Ql[BM * QSTRIDE];
    __shared__ __bf16 Kh[BM * QSTRIDE];
    __shared__ __bf16 Kl[BM * QSTRIDE];
    __shared__ __bf16 Vt[DH * VTSTRIDE];   // transposed: Vt[dh][krow]
    __shared__ __bf16 Pt[BM * PTSTRIDE];
    __shared__ float Fq[BM], Fk[BM], Igk[BM];
    __shared__ float mrow[BM], lrow[BM], alpharow[BM];
    __shared__ float tmax[2][BM], tsum[2][BM];

    const float* Fh  = F  + h * (S_LEN + 1);
    const float* igh = ig + h * S_LEN;
    const float scale = 0.088388347648318447f; // 1/sqrt(128)

    for (int pair = 0; pair < 2; ++pair) {
        const int qt = (pair == 0) ? (int)blockIdx.x : 63 - (int)blockIdx.x;
        const int qb = qt * BM;
        __syncthreads(); // S0: previous pair fully done
        if (tid < BM) { Fq[tid] = Fh[qb + tid + 1]; mrow[tid] = -INFINITY; lrow[tid] = 0.f; }
        // stage Q tile (32 x 128 fp32 -> hi/lo bf16)
        #pragma unroll
        for (int i = 0; i < 4; ++i) {
            int f4 = tid + i * 256;
            int row = f4 >> 5, c4 = f4 & 31;
            float4 val = *(const float4*)(q + (size_t)(qb + row) * EMB + h * DH + c4 * 4);
            __bf16* dh_ = &Qh[row * QSTRIDE + c4 * 4];
            __bf16* dl_ = &Ql[row * QSTRIDE + c4 * 4];
            __bf16 h0 = (__bf16)val.x, h1 = (__bf16)val.y, h2 = (__bf16)val.z, h3 = (__bf16)val.w;
            dh_[0] = h0; dh_[1] = h1; dh_[2] = h2; dh_[3] = h3;
            dl_[0] = (__bf16)(val.x - (float)h0);
            dl_[1] = (__bf16)(val.y - (float)h1);
            dl_[2] = (__bf16)(val.z - (float)h2);
            dl_[3] = (__bf16)(val.w - (float)h3);
        }
        f32x4 Oacc[4] = {{0,0,0,0},{0,0,0,0},{0,0,0,0},{0,0,0,0}};

        for (int j = 0; j <= qt; ++j) {
            const int tb = j * BM;
            __syncthreads(); // A: prev-iter Pt/Vt consumers done; init/Q visible
            // ---- stage K tile (hi/lo, row-major) + V tile (transposed) ----
            #pragma unroll
            for (int i = 0; i < 4; ++i) {
                int f4 = tid + i * 256;
                int row = f4 >> 5, c4 = f4 & 31;
                float4 kv = *(const float4*)(k + (size_t)(tb + row) * EMB + h * DH + c4 * 4);
                __bf16* dh_ = &Kh[row * QSTRIDE + c4 * 4];
                __bf16* dl_ = &Kl[row * QSTRIDE + c4 * 4];
                __bf16 h0 = (__bf16)kv.x, h1 = (__bf16)kv.y, h2 = (__bf16)kv.z, h3 = (__bf16)kv.w;
                dh_[0] = h0; dh_[1] = h1; dh_[2] = h2; dh_[3] = h3;
                dl_[0] = (__bf16)(kv.x - (float)h0);
                dl_[1] = (__bf16)(kv.y - (float)h1);
                dl_[2] = (__bf16)(kv.z - (float)h2);
                dl_[3] = (__bf16)(kv.w - (float)h3);
                float4 vv = *(const float4*)(v + (size_t)(tb + row) * EMB + h * DH + c4 * 4);
                int dh = c4 * 4;
                Vt[(dh + 0) * VTSTRIDE + row] = (__bf16)vv.x;
                Vt[(dh + 1) * VTSTRIDE + row] = (__bf16)vv.y;
                Vt[(dh + 2) * VTSTRIDE + row] = (__bf16)vv.z;
                Vt[(dh + 3) * VTSTRIDE + row] = (__bf16)vv.w;
            }
            if (tid < BM) { Fk[tid] = Fh[tb + tid + 1]; Igk[tid] = igh[tb + tid]; }
            __syncthreads(); // B
            // ---- S = Q K^T via split-bf16: Qh*Kh + Qh*Kl + Ql*Kh ----
            f32x4 Sacc = {0, 0, 0, 0};
            #pragma unroll
            for (int kk = 0; kk < 4; ++kk) {
                const int ao = (mi * 16 + l15) * QSTRIDE + kk * 32 + quad * 8;
                const int bo = (ni * 16 + l15) * QSTRIDE + kk * 32 + quad * 8;
                bf16x8 ah = *(const bf16x8*)(&Qh[ao]);
                bf16x8 al = *(const bf16x8*)(&Ql[ao]);
                bf16x8 bh = *(const bf16x8*)(&Kh[bo]);
                bf16x8 bl = *(const bf16x8*)(&Kl[bo]);
                Sacc = __builtin_amdgcn_mfma_f32_16x16x32_bf16(ah, bh, Sacc, 0, 0, 0);
                Sacc = __builtin_amdgcn_mfma_f32_16x16x32_bf16(ah, bl, Sacc, 0, 0, 0);
                Sacc = __builtin_amdgcn_mfma_f32_16x16x32_bf16(al, bh, Sacc, 0, 0, 0);
            }
            // ---- gate matrix + per-row tile max ----
            const int tc = ni * 16 + l15;
            const float fkv = Fk[tc], igv = Igk[tc];
            const int tglob = tb + tc;
            float g[4];
            #pragma unroll
            for (int r = 0; r < 4; ++r) {
                int ri = mi * 16 + quad * 4 + r;
                int sglob = qb + ri;
                g[r] = (tglob <= sglob) ? (Fq[ri] - fkv + igv) : -INFINITY;
                float x = g[r];
                #pragma unroll
                for (int o = 1; o < 16; o <<= 1) x = fmaxf(x, __shfl_xor(x, o));
                if (l15 == 0) tmax[ni][ri] = x;
            }
            __syncthreads(); // C
            if (ni == 0 && l15 == 0) {
                #pragma unroll
                for (int r = 0; r < 4; ++r) {
                    int ri = mi * 16 + quad * 4 + r;
                    float mo = mrow[ri];
                    float mn = fmaxf(mo, fmaxf(tmax[0][ri], tmax[1][ri]));
                    mrow[ri] = mn;
                    alpharow[ri] = expf(mo - mn);
                }
            }
            __syncthreads(); // C2
            // ---- P = exp(g - m_new) * S * scale; row sums; Pt to LDS ----
            #pragma unroll
            for (int r = 0; r < 4; ++r) {
                int ri = mi * 16 + quad * 4 + r;
                float mn = mrow[ri];
                float p = expf(g[r] - mn) * Sacc[r] * scale;
                float x = p;
                #pragma unroll
                for (int o = 1; o < 16; o <<= 1) x += __shfl_xor(x, o);
                if (l15 == 0) tsum[ni][ri] = x;
                Pt[ri * PTSTRIDE + ni * 16 + l15] = (__bf16)p;
                float al = alpharow[ri];
                Oacc[0][r] *= al; Oacc[1][r] *= al; Oacc[2][r] *= al; Oacc[3][r] *= al;
            }
            __syncthreads(); // D
            if (ni == 0 && l15 == 0) {
                #pragma unroll
                for (int r = 0; r < 4; ++r) {
                    int ri = mi * 16 + quad * 4 + r;
                    lrow[ri] = lrow[ri] * alpharow[ri] + tsum[0][ri] + tsum[1][ri];
                }
            }
            // ---- O += P V (wave covers rows mi*16.., cols ni*64..+64) ----
            bf16x8 pa = *(const bf16x8*)(&Pt[(mi * 16 + l15) * PTSTRIDE + quad * 8]);
            #pragma unroll
            for (int nt = 0; nt < 4; ++nt) {
                int n = ni * 64 + nt * 16 + l15;
                bf16x4 lo = *(const bf16x4*)(&Vt[n * VTSTRIDE + quad * 8]);
                bf16x4 hi = *(const bf16x4*)(&Vt[n * VTSTRIDE + quad * 8 + 4]);
                bf16x8 b;
                b[0] = lo[0]; b[1] = lo[1]; b[2] = lo[2]; b[3] = lo[3];
                b[4] = hi[0]; b[5] = hi[1]; b[6] = hi[2]; b[7] = hi[3];
                Oacc[nt] = __builtin_amdgcn_mfma_f32_16x16x32_bf16(pa, b, Oacc[nt], 0, 0, 0);
            }
        }
        __syncthreads(); // E: final lrow/mrow visible
        float rnorm[4];
        #pragma unroll
        for (int r = 0; r < 4; ++r) {
            int ri = mi * 16 + quad * 4 + r;
            rnorm[r] = 1.f / (fmaxf(fabsf(lrow[ri]), expf(-mrow[ri])) + 1e-6f);
        }
        #pragma unroll
        for (int nt = 0; nt < 4; ++nt) {
            #pragma unroll
            for (int r = 0; r < 4; ++r) {
                int ri = mi * 16 + quad * 4 + r;
                out[(size_t)(qb + ri) * EMB + h * DH + ni * 64 + nt * 16 + l15] =
                    Oacc[nt][r] * rnorm[r];
            }
        }
    }
}

// ---------------------------------------------------------------------------
// Kernel 4: in-place residual LayerNorm (unchanged).
// ---------------------------------------------------------------------------
__global__ __launch_bounds__(256) void ln_kernel(
    float* __restrict__ out, const float* __restrict__ lnw)
{
    const int s = blockIdx.x, tid = threadIdx.x;
    __shared__ float red[4];
    float x[4];
    float sum = 0.f;
    #pragma unroll
    for (int i = 0; i < 4; i++) {
        x[i] = out[(size_t)s * EMB + tid + i * 256];
        sum += x[i];
    }
    for (int o = 32; o > 0; o >>= 1) sum += __shfl_down(sum, o, 64);
    if ((tid & 63) == 0) red[tid >> 6] = sum;
    __syncthreads();
    sum = red[0] + red[1] + red[2] + red[3];
    const float mu = sum * (1.f / EMB);
    float vs = 0.f;
    #pragma unroll
    for (int i = 0; i < 4; i++) { float d = x[i] - mu; vs += d * d; }
    __syncthreads();
    for (int o = 32; o > 0; o >>= 1) vs += __shfl_down(vs, o, 64);
    if ((tid & 63) == 0) red[tid >> 6] = vs;
    __syncthreads();
    vs = red[0] + red[1] + red[2] + red[3];
    const float rstd = rsqrtf(vs * (1.f / EMB) + 1e-5f);
    #pragma unroll
    for (int i = 0; i < 4; i++) {
        int c = tid + i * 256;
        out[(size_t)s * EMB + c] = (x[i] - mu) * rstd * (1.f + lnw[c]);
    }
}

// ---------------------------------------------------------------------------
extern "C" void kernel_launch(void* const* d_in, const int* in_sizes, int n_in,
                              void* d_out, int out_size, void* d_ws, size_t ws_size,
                              hipStream_t stream)
{
    const float* q   = (const float*)d_in[0];
    const float* k   = (const float*)d_in[1];
    const float* v   = (const float*)d_in[2];
    const float* Wi  = (const float*)d_in[3];
    const float* bi  = (const float*)d_in[4];
    const float* Wf  = (const float*)d_in[5];
    const float* bf  = (const float*)d_in[6];
    const float* lnw = (const float*)d_in[7];
    float* out = (float*)d_out;

    float* ws = (float*)d_ws;
    float* ig = ws;
    float* lf = ws + NHEAD * S_LEN;
    float* F  = ws + 2 * NHEAD * S_LEN;

    gates_kernel<<<dim3(S_LEN, NHEAD), 64, 0, stream>>>(q, k, v, Wi, bi, Wf, bf, ig, lf);
    cumsum_kernel<<<NHEAD, 256, 0, stream>>>(lf, F);
    mlstm_mfma<<<dim3(32, NHEAD), 256, 0, stream>>>(q, k, v, ig, F, out);
    ln_kernel<<<S_LEN, 256, 0, stream>>>(out, lnw);
}

// Round 4
// 223.167 us; speedup vs baseline: 13.6084x; 1.5861x over previous
//
#include <hip/hip_runtime.h>
#include <math.h>

#define S_LEN 2048
#define EMB   1024
#define NHEAD 8
#define DH    128
#define E3    3072
#define BM    32
#define NSPLIT 3
#define QSTRIDE  136   // Q/K LDS row stride (elems): 272B rows, b128-aligned, conflict-free frag reads
#define VTSTRIDE 36    // V^T LDS row stride: 72B rows, b64-aligned, ~2-way banks
#define PTSTRIDE 40    // P LDS row stride: 80B rows, b128-aligned

typedef __bf16 bf16x8 __attribute__((ext_vector_type(8)));
typedef __bf16 bf16x4 __attribute__((ext_vector_type(4)));
typedef float  f32x4  __attribute__((ext_vector_type(4)));

// ---------------------------------------------------------------------------
// Pre-pass 1: q,k fp32 -> hi/lo bf16 split arrays (same [S][EMB] layout).
// ---------------------------------------------------------------------------
__global__ __launch_bounds__(256) void cvt_qk_kernel(
    const float* __restrict__ q, const float* __restrict__ k,
    __bf16* __restrict__ Qh, __bf16* __restrict__ Ql,
    __bf16* __restrict__ Kh, __bf16* __restrict__ Kl)
{
    const int N4 = S_LEN * EMB / 4;
    int idx = blockIdx.x * 256 + threadIdx.x;
    if (idx >= 2 * N4) return;
    const float* src; __bf16 *dh, *dl; int i = idx;
    if (i < N4) { src = q; dh = Qh; dl = Ql; }
    else        { src = k; dh = Kh; dl = Kl; i -= N4; }
    float4 val = ((const float4*)src)[i];
    bf16x4 hi, lo;
    hi[0] = (__bf16)val.x; hi[1] = (__bf16)val.y;
    hi[2] = (__bf16)val.z; hi[3] = (__bf16)val.w;
    lo[0] = (__bf16)(val.x - (float)hi[0]);
    lo[1] = (__bf16)(val.y - (float)hi[1]);
    lo[2] = (__bf16)(val.z - (float)hi[2]);
    lo[3] = (__bf16)(val.w - (float)hi[3]);
    ((bf16x4*)dh)[i] = hi;
    ((bf16x4*)dl)[i] = lo;
}

// ---------------------------------------------------------------------------
// Pre-pass 2: v fp32 [S][EMB] -> bf16 V^T [EMB][S] (== [NH][DH][S]).
// 32x32 LDS tile transpose, coalesced both sides.
// ---------------------------------------------------------------------------
__global__ __launch_bounds__(256) void transpose_v_kernel(
    const float* __restrict__ v, __bf16* __restrict__ Vt)
{
    __shared__ __bf16 tile[32][33];
    const int sb = blockIdx.x * 32, eb = blockIdx.y * 32;
    #pragma unroll
    for (int i = 0; i < 4; ++i) {
        int lin = threadIdx.x + i * 256;
        int sr = lin >> 5, ec = lin & 31;
        tile[ec][sr] = (__bf16)v[(size_t)(sb + sr) * EMB + eb + ec];
    }
    __syncthreads();
    #pragma unroll
    for (int i = 0; i < 4; ++i) {
        int lin = threadIdx.x + i * 256;
        int er = lin >> 5, sc = lin & 31;
        Vt[(size_t)(eb + er) * S_LEN + sb + sc] = tile[er][sc];
    }
}

// ---------------------------------------------------------------------------
// Gates: one block per row t, all 8 heads at once (q/k/v row read ONCE).
// ---------------------------------------------------------------------------
__global__ __launch_bounds__(256) void gates_kernel(
    const float* __restrict__ q, const float* __restrict__ k,
    const float* __restrict__ v,
    const float* __restrict__ Wi, const float* __restrict__ bi,
    const float* __restrict__ Wf, const float* __restrict__ bf,
    float* __restrict__ ig, float* __restrict__ lf)
{
    const int t = blockIdx.x, tid = threadIdx.x;
    const float4 qv = *(const float4*)(q + (size_t)t * EMB + tid * 4);
    const float4 kv = *(const float4*)(k + (size_t)t * EMB + tid * 4);
    const float4 vv = *(const float4*)(v + (size_t)t * EMB + tid * 4);
    float acc[16];
    #pragma unroll
    for (int h = 0; h < NHEAD; ++h) {
        const float* wi = Wi + h * E3;
        const float* wf = Wf + h * E3;
        float4 a = *(const float4*)(wi + tid * 4);
        float4 b = *(const float4*)(wi + EMB + tid * 4);
        float4 c = *(const float4*)(wi + 2 * EMB + tid * 4);
        acc[2 * h] = a.x * qv.x + a.y * qv.y + a.z * qv.z + a.w * qv.w
                   + b.x * kv.x + b.y * kv.y + b.z * kv.z + b.w * kv.w
                   + c.x * vv.x + c.y * vv.y + c.z * vv.z + c.w * vv.w;
        float4 d = *(const float4*)(wf + tid * 4);
        float4 e = *(const float4*)(wf + EMB + tid * 4);
        float4 f = *(const float4*)(wf + 2 * EMB + tid * 4);
        acc[2 * h + 1] = d.x * qv.x + d.y * qv.y + d.z * qv.z + d.w * qv.w
                       + e.x * kv.x + e.y * kv.y + e.z * kv.z + e.w * kv.w
                       + f.x * vv.x + f.y * vv.y + f.z * vv.z + f.w * vv.w;
    }
    __shared__ float red[16][4];
    const int w = tid >> 6, lane = tid & 63;
    #pragma unroll
    for (int g = 0; g < 16; ++g) {
        float x = acc[g];
        for (int o = 32; o > 0; o >>= 1) x += __shfl_down(x, o, 64);
        if (lane == 0) red[g][w] = x;
    }
    __syncthreads();
    if (tid < 16) {
        float s = red[tid][0] + red[tid][1] + red[tid][2] + red[tid][3];
        int h = tid >> 1;
        if ((tid & 1) == 0) {
            ig[h * S_LEN + t] = s + bi[h];
        } else {
            float x = s + bf[h];
            lf[h * S_LEN + t] = fminf(x, 0.f) - log1pf(expf(-fabsf(x)));
        }
    }
}

// ---------------------------------------------------------------------------
// Per-head inclusive cumsum of lf -> F[h][0..S] (unchanged).
// ---------------------------------------------------------------------------
__global__ __launch_bounds__(256) void cumsum_kernel(
    const float* __restrict__ lf, float* __restrict__ F)
{
    const int h = blockIdx.x, tid = threadIdx.x;
    __shared__ float ssum[256];
    float loc[8];
    const int base = tid * 8;
    float s = 0.f;
    for (int i = 0; i < 8; i++) { s += lf[h * S_LEN + base + i]; loc[i] = s; }
    ssum[tid] = s;
    __syncthreads();
    for (int o = 1; o < 256; o <<= 1) {
        float add = (tid >= o) ? ssum[tid - o] : 0.f;
        __syncthreads();
        ssum[tid] += add;
        __syncthreads();
    }
    float prev = (tid > 0) ? ssum[tid - 1] : 0.f;
    float* Fh = F + h * (S_LEN + 1);
    if (tid == 0) Fh[0] = 0.f;
    for (int i = 0; i < 8; i++) Fh[base + i + 1] = prev + loc[i];
}

// ---------------------------------------------------------------------------
// Main: flash mLSTM, split-bf16 QK^T, split-K x3 across blockIdx.z.
// Grid (32, NH, 3), 256 thr. wg x does Q-tiles {x, 63-x}; z takes a third of
// each tile's K-range. Writes unnormalized O + per-row (m, l) partials.
// 4 barriers/tile; staging = b64 copies of pre-converted bf16 w/ reg prefetch.
// ---------------------------------------------------------------------------
__global__ __launch_bounds__(256, 3) void mlstm_mfma(
    const __bf16* __restrict__ Qhg, const __bf16* __restrict__ Qlg,
    const __bf16* __restrict__ Khg, const __bf16* __restrict__ Klg,
    const __bf16* __restrict__ Vtg,
    const float* __restrict__ ig, const float* __restrict__ F,
    float* __restrict__ Opart, float* __restrict__ msplit,
    float* __restrict__ lsplit)
{
    const int h = blockIdx.y, z = blockIdx.z;
    const int tid  = threadIdx.x;
    const int lane = tid & 63, w = tid >> 6;
    const int quad = lane >> 4, l15 = lane & 15;
    const int mi = w & 1, ni = w >> 1;

    __shared__ __bf16 Qh[BM * QSTRIDE], Ql[BM * QSTRIDE];
    __shared__ __bf16 Kh[BM * QSTRIDE], Kl[BM * QSTRIDE];
    __shared__ __bf16 Vt[DH * VTSTRIDE];
    __shared__ __bf16 Pt[BM * PTSTRIDE];
    __shared__ float tmax[2][BM], tsum[2][BM];

    const float* Fh  = F  + h * (S_LEN + 1);
    const float* igh = ig + h * S_LEN;
    const float scale = 0.088388347648318447f; // 1/sqrt(128)
    const int kr0 = tid >> 5, kc4 = tid & 31;  // K staging: chunk rows/cols
    const int vr0 = tid >> 3, vc  = tid & 7;   // Vt staging

    for (int pair = 0; pair < 2; ++pair) {
        const int qt = (pair == 0) ? (int)blockIdx.x : 63 - (int)blockIdx.x;
        const int qb = qt * BM;
        const int nj = qt + 1;
        const int j0 = (z * nj) / NSPLIT, j1 = ((z + 1) * nj) / NSPLIT;

        __syncthreads(); // S0: previous pair's LDS consumers done
        // stage Q hi/lo (pure b64 copies)
        #pragma unroll
        for (int i = 0; i < 4; ++i) {
            int row = kr0 + i * 8;
            size_t g = (size_t)(qb + row) * EMB + h * DH + kc4 * 4;
            *(bf16x4*)&Qh[row * QSTRIDE + kc4 * 4] = *(const bf16x4*)(Qhg + g);
            *(bf16x4*)&Ql[row * QSTRIDE + kc4 * 4] = *(const bf16x4*)(Qlg + g);
        }
        float fq[4];
        #pragma unroll
        for (int r = 0; r < 4; ++r) fq[r] = Fh[qb + mi * 16 + quad * 4 + r + 1];
        float m_r[4] = {-INFINITY, -INFINITY, -INFINITY, -INFINITY};
        float l_r[4] = {0.f, 0.f, 0.f, 0.f};
        f32x4 Oacc[4] = {{0,0,0,0},{0,0,0,0},{0,0,0,0},{0,0,0,0}};

        bf16x4 pk[4], pl[4], pv[4];
        if (j0 < j1) {
            const int tb = j0 * BM;
            #pragma unroll
            for (int i = 0; i < 4; ++i) {
                int row = kr0 + i * 8;
                size_t g = (size_t)(tb + row) * EMB + h * DH + kc4 * 4;
                pk[i] = *(const bf16x4*)(Khg + g);
                pl[i] = *(const bf16x4*)(Klg + g);
                int vr = vr0 + i * 32;
                pv[i] = *(const bf16x4*)(Vtg + (size_t)(h * DH + vr) * S_LEN + tb + vc * 4);
            }
        }

        for (int j = j0; j < j1; ++j) {
            const int tb = j * BM;
            __syncthreads(); // A: prev-iter LDS consumers done
            #pragma unroll
            for (int i = 0; i < 4; ++i) {
                int row = kr0 + i * 8;
                *(bf16x4*)&Kh[row * QSTRIDE + kc4 * 4] = pk[i];
                *(bf16x4*)&Kl[row * QSTRIDE + kc4 * 4] = pl[i];
                int vr = vr0 + i * 32;
                *(bf16x4*)&Vt[vr * VTSTRIDE + vc * 4] = pv[i];
            }
            __syncthreads(); // B: tiles staged
            if (j + 1 < j1) {  // prefetch next tile (overlaps MFMA + barriers)
                const int tb2 = tb + BM;
                #pragma unroll
                for (int i = 0; i < 4; ++i) {
                    int row = kr0 + i * 8;
                    size_t g = (size_t)(tb2 + row) * EMB + h * DH + kc4 * 4;
                    pk[i] = *(const bf16x4*)(Khg + g);
                    pl[i] = *(const bf16x4*)(Klg + g);
                    int vr = vr0 + i * 32;
                    pv[i] = *(const bf16x4*)(Vtg + (size_t)(h * DH + vr) * S_LEN + tb2 + vc * 4);
                }
            }
            // ---- S = Q K^T (split-bf16: Qh*Kh + Qh*Kl + Ql*Kh) ----
            f32x4 Sacc = {0, 0, 0, 0};
            #pragma unroll
            for (int kk = 0; kk < 4; ++kk) {
                const int ao = (mi * 16 + l15) * QSTRIDE + kk * 32 + quad * 8;
                const int bo = (ni * 16 + l15) * QSTRIDE + kk * 32 + quad * 8;
                bf16x8 ah = *(const bf16x8*)&Qh[ao];
                bf16x8 al = *(const bf16x8*)&Ql[ao];
                bf16x8 bh = *(const bf16x8*)&Kh[bo];
                bf16x8 bl = *(const bf16x8*)&Kl[bo];
                Sacc = __builtin_amdgcn_mfma_f32_16x16x32_bf16(ah, bh, Sacc, 0, 0, 0);
                Sacc = __builtin_amdgcn_mfma_f32_16x16x32_bf16(ah, bl, Sacc, 0, 0, 0);
                Sacc = __builtin_amdgcn_mfma_f32_16x16x32_bf16(al, bh, Sacc, 0, 0, 0);
            }
            // ---- gates + per-row tile max (no serial section) ----
            const int tc = ni * 16 + l15;
            const float fkv = Fh[tb + tc + 1], igv = igh[tb + tc];
            float g[4];
            #pragma unroll
            for (int r = 0; r < 4; ++r) {
                int ri = mi * 16 + quad * 4 + r;
                g[r] = (tb + tc <= qb + ri) ? (fq[r] - fkv + igv) : -INFINITY;
                float x = g[r];
                #pragma unroll
                for (int o = 1; o < 16; o <<= 1) x = fmaxf(x, __shfl_xor(x, o));
                if (l15 == 0) tmax[ni][ri] = x;
            }
            __syncthreads(); // C: tmax halves visible
            #pragma unroll
            for (int r = 0; r < 4; ++r) {
                int ri = mi * 16 + quad * 4 + r;
                float mn = fmaxf(m_r[r], fmaxf(tmax[0][ri], tmax[1][ri]));
                float alpha = expf(m_r[r] - mn);   // first tile: exp(-inf)=0
                m_r[r] = mn;
                l_r[r] *= alpha;
                Oacc[0][r] *= alpha; Oacc[1][r] *= alpha;
                Oacc[2][r] *= alpha; Oacc[3][r] *= alpha;
                float p = expf(g[r] - mn) * Sacc[r] * scale;
                float x = p;
                #pragma unroll
                for (int o = 1; o < 16; o <<= 1) x += __shfl_xor(x, o);
                if (l15 == 0) tsum[ni][ri] = x;
                Pt[ri * PTSTRIDE + tc] = (__bf16)p;
            }
            __syncthreads(); // D: tsum + Pt visible
            #pragma unroll
            for (int r = 0; r < 4; ++r) {
                int ri = mi * 16 + quad * 4 + r;
                l_r[r] += tsum[0][ri] + tsum[1][ri];
            }
            // ---- O += P V ----
            bf16x8 pa = *(const bf16x8*)&Pt[(mi * 16 + l15) * PTSTRIDE + quad * 8];
            #pragma unroll
            for (int nt = 0; nt < 4; ++nt) {
                int n = ni * 64 + nt * 16 + l15;
                bf16x4 lo = *(const bf16x4*)&Vt[n * VTSTRIDE + quad * 8];
                bf16x4 hi = *(const bf16x4*)&Vt[n * VTSTRIDE + quad * 8 + 4];
                bf16x8 b;
                b[0] = lo[0]; b[1] = lo[1]; b[2] = lo[2]; b[3] = lo[3];
                b[4] = hi[0]; b[5] = hi[1]; b[6] = hi[2]; b[7] = hi[3];
                Oacc[nt] = __builtin_amdgcn_mfma_f32_16x16x32_bf16(pa, b, Oacc[nt], 0, 0, 0);
            }
        }
        // ---- epilogue: unnormalized partials ----
        float* Oz = Opart + (size_t)z * S_LEN * EMB;
        #pragma unroll
        for (int nt = 0; nt < 4; ++nt) {
            #pragma unroll
            for (int r = 0; r < 4; ++r) {
                int ri = mi * 16 + quad * 4 + r;
                Oz[(size_t)(qb + ri) * EMB + h * DH + ni * 64 + nt * 16 + l15] = Oacc[nt][r];
            }
        }
        if (ni == 0 && l15 == 0) {
            #pragma unroll
            for (int r = 0; r < 4; ++r) {
                int ri = mi * 16 + quad * 4 + r;
                msplit[(z * NHEAD + h) * S_LEN + qb + ri] = m_r[r];
                lsplit[(z * NHEAD + h) * S_LEN + qb + ri] = l_r[r];
            }
        }
    }
}

// ---------------------------------------------------------------------------
// Combine split-K partials + normalize + residual LayerNorm, fused.
// ---------------------------------------------------------------------------
__global__ __launch_bounds__(256) void combine_ln_kernel(
    const float* __restrict__ Opart, const float* __restrict__ msplit,
    const float* __restrict__ lsplit, const float* __restrict__ lnw,
    float* __restrict__ out)
{
    const int s = blockIdx.x, tid = threadIdx.x;
    __shared__ float es_s[NSPLIT][NHEAD];
    __shared__ float rn_s[NHEAD];
    __shared__ float red[4];
    if (tid < NHEAD) {
        float m0 = msplit[(0 * NHEAD + tid) * S_LEN + s];
        float m1 = msplit[(1 * NHEAD + tid) * S_LEN + s];
        float m2 = msplit[(2 * NHEAD + tid) * S_LEN + s];
        float m = fmaxf(m0, fmaxf(m1, m2));
        float e0 = expf(m0 - m), e1 = expf(m1 - m), e2 = expf(m2 - m);
        float l = e0 * lsplit[(0 * NHEAD + tid) * S_LEN + s]
                + e1 * lsplit[(1 * NHEAD + tid) * S_LEN + s]
                + e2 * lsplit[(2 * NHEAD + tid) * S_LEN + s];
        es_s[0][tid] = e0; es_s[1][tid] = e1; es_s[2][tid] = e2;
        rn_s[tid] = 1.f / (fmaxf(fabsf(l), expf(-m)) + 1e-6f);
    }
    __syncthreads();
    const size_t SE = (size_t)S_LEN * EMB;
    float x[4];
    float sum = 0.f;
    #pragma unroll
    for (int i = 0; i < 4; i++) {
        int col = tid + i * 256;
        int hh = col >> 7;
        size_t off = (size_t)s * EMB + col;
        float val = es_s[0][hh] * Opart[off]
                  + es_s[1][hh] * Opart[SE + off]
                  + es_s[2][hh] * Opart[2 * SE + off];
        x[i] = val * rn_s[hh];
        sum += x[i];
    }
    for (int o = 32; o > 0; o >>= 1) sum += __shfl_down(sum, o, 64);
    if ((tid & 63) == 0) red[tid >> 6] = sum;
    __syncthreads();
    sum = red[0] + red[1] + red[2] + red[3];
    const float mu = sum * (1.f / EMB);
    float vs = 0.f;
    #pragma unroll
    for (int i = 0; i < 4; i++) { float d = x[i] - mu; vs += d * d; }
    __syncthreads();
    for (int o = 32; o > 0; o >>= 1) vs += __shfl_down(vs, o, 64);
    if ((tid & 63) == 0) red[tid >> 6] = vs;
    __syncthreads();
    vs = red[0] + red[1] + red[2] + red[3];
    const float rstd = rsqrtf(vs * (1.f / EMB) + 1e-5f);
    #pragma unroll
    for (int i = 0; i < 4; i++) {
        int c = tid + i * 256;
        out[(size_t)s * EMB + c] = (x[i] - mu) * rstd * (1.f + lnw[c]);
    }
}

// ---------------------------------------------------------------------------
extern "C" void kernel_launch(void* const* d_in, const int* in_sizes, int n_in,
                              void* d_out, int out_size, void* d_ws, size_t ws_size,
                              hipStream_t stream)
{
    const float* q   = (const float*)d_in[0];
    const float* k   = (const float*)d_in[1];
    const float* v   = (const float*)d_in[2];
    const float* Wi  = (const float*)d_in[3];
    const float* bi  = (const float*)d_in[4];
    const float* Wf  = (const float*)d_in[5];
    const float* bf  = (const float*)d_in[6];
    const float* lnw = (const float*)d_in[7];
    float* out = (float*)d_out;

    // workspace layout (floats):
    // ig 16384 | lf 16384 | F 16392 | Qh/Ql/Kh/Kl/Vt bf16 (1048576 f each)
    // | Opart 3*S*EMB | msplit 3*NH*S | lsplit 3*NH*S        (~44.6 MB total)
    float* ws = (float*)d_ws;
    float* ig = ws;
    float* lf = ig + NHEAD * S_LEN;
    float* F  = lf + NHEAD * S_LEN;
    __bf16* Qh = (__bf16*)(F + NHEAD * (S_LEN + 1));
    const size_t SEb = (size_t)S_LEN * EMB;        // bf16 elems per array
    __bf16* Ql  = Qh + SEb;
    __bf16* Kh  = Ql + SEb;
    __bf16* Kl  = Kh + SEb;
    __bf16* Vtg = Kl + SEb;
    float* Opart  = (float*)(Vtg + SEb);
    float* msplit = Opart + (size_t)NSPLIT * S_LEN * EMB;
    float* lsplit = msplit + NSPLIT * NHEAD * S_LEN;

    cvt_qk_kernel<<<(2 * S_LEN * EMB / 4 + 255) / 256, 256, 0, stream>>>(
        q, k, Qh, Ql, Kh, Kl);
    transpose_v_kernel<<<dim3(S_LEN / 32, EMB / 32), 256, 0, stream>>>(v, Vtg);
    gates_kernel<<<S_LEN, 256, 0, stream>>>(q, k, v, Wi, bi, Wf, bf, ig, lf);
    cumsum_kernel<<<NHEAD, 256, 0, stream>>>(lf, F);
    mlstm_mfma<<<dim3(32, NHEAD, NSPLIT), 256, 0, stream>>>(
        Qh, Ql, Kh, Kl, Vtg, ig, F, Opart, msplit, lsplit);
    combine_ln_kernel<<<S_LEN, 256, 0, stream>>>(Opart, msplit, lsplit, lnw, out);
}